// Round 3
// baseline (146.337 us; speedup 1.0000x reference)
//
#include <hip/hip_runtime.h>
#include <math.h>

#define BB 128   // batch
#define TT 8     // seq
#define DD 2048  // model dim
#define RR 4     // TT rank
#define VV 512   // vocab

typedef __attribute__((ext_vector_type(8))) short short8;
typedef __attribute__((ext_vector_type(4))) float v4f;

__device__ __forceinline__ unsigned pack_bf16(float x, float y) {
    union { float f; unsigned u; } a, b;
    a.f = x; b.f = y;
    unsigned ua = a.u + 0x7fffu + ((a.u >> 16) & 1u);
    unsigned ub = b.u + 0x7fffu + ((b.u >> 16) & 1u);
    return (ua >> 16) | (ub & 0xffff0000u);
}

// ---------------- phase A: T-mean -> fmb(bf16), alpha/beta half-partials, zero marg ----------------
// grid 256 = (b, half-of-D). No atomics: block (b,half) writes alphaP[half][b][r].
// Block 0 zeroes marg (safe: phaseB is stream-ordered after phaseA).
__global__ __launch_bounds__(256) void phaseA(const float* __restrict__ inp,
                                              const float* __restrict__ w_alpha,
                                              const float* __restrict__ w_beta,
                                              unsigned short* __restrict__ fmb,
                                              float* __restrict__ alphaP,
                                              float* __restrict__ betaP,
                                              float* __restrict__ marg) {
    int bid = blockIdx.x;
    int b = bid >> 1, half = bid & 1;
    int tid = threadIdx.x;
    if (bid == 0) {
#pragma unroll
        for (int e = 0; e < 8; ++e) marg[e * 256 + tid] = 0.f;
    }
    const float* base = inp + (size_t)b * TT * DD;
    float pa[4] = {0.f, 0.f, 0.f, 0.f};
    float pb[4] = {0.f, 0.f, 0.f, 0.f};
#pragma unroll
    for (int i = 0; i < 4; ++i) {
        int d = half * 1024 + i * 256 + tid;
        float s = 0.f;
#pragma unroll
        for (int t = 0; t < TT; ++t) s += base[t * DD + d];
        float v = s * (1.0f / TT);
        union { float f; unsigned u; } cv; cv.f = v;
        unsigned r = cv.u + 0x7fffu + ((cv.u >> 16) & 1u);
        fmb[b * DD + d] = (unsigned short)(r >> 16);
        float4 wa = *(const float4*)(w_alpha + d * 4);
        float4 wb = *(const float4*)(w_beta + d * 4);
        pa[0] += v * wa.x; pa[1] += v * wa.y; pa[2] += v * wa.z; pa[3] += v * wa.w;
        pb[0] += v * wb.x; pb[1] += v * wb.y; pb[2] += v * wb.z; pb[3] += v * wb.w;
    }
#pragma unroll
    for (int r = 0; r < 4; ++r) {
        for (int m = 1; m < 64; m <<= 1) {
            pa[r] += __shfl_xor(pa[r], m);
            pb[r] += __shfl_xor(pb[r], m);
        }
    }
    __shared__ float red[4][8];
    if ((tid & 63) == 0) {
        int w = tid >> 6;
#pragma unroll
        for (int r = 0; r < 4; ++r) { red[w][r] = pa[r]; red[w][4 + r] = pb[r]; }
    }
    __syncthreads();
    if (tid < 8) {
        float s = red[0][tid] + red[1][tid] + red[2][tid] + red[3][tid];
        if (tid < 4) alphaP[(half * BB + b) * 4 + tid] = s;
        else         betaP[(half * BB + b) * 4 + (tid - 4)] = s;
    }
}

// ---------------- phase B: bf16 MFMA GEMM + fused abs/marg/select epilogue ----------------
// grid 512 blocks x 256 thr (2 blocks/CU): block nb covers cols [nb*16, +16), full K=2048.
// 4 waves; wave w rows [w*32, +32) = 2 row-tiles sharing one B-frag. Ws double-buffered.
__global__ __launch_bounds__(256, 4) void phaseB(const unsigned short* __restrict__ fmb,
                                                 const float* __restrict__ wv,
                                                 const int* __restrict__ labels,
                                                 float* __restrict__ marg,
                                                 float* __restrict__ sel) {
    __shared__ unsigned short Ws[2][16][136];  // [buf][n][k+pad], bf16
    __shared__ int slab[BB * TT];

    const int tid = threadIdx.x;
    const int nb = blockIdx.x;
    const int col0 = nb * 16;
    const int iblk = nb >> 7;   // i index [0,4)
    const int c128 = nb & 127;  // vocab-quad index

    slab[tid] = labels[tid];
    slab[tid + 256] = labels[tid + 256];
    slab[tid + 512] = labels[tid + 512];
    slab[tid + 768] = labels[tid + 768];

    const int c4 = tid & 3;        // col quad
    const int kp = tid >> 2;       // 0..63 -> rows 2kp, 2kp+1 of the k-chunk
    const int w = tid >> 6;        // wave
    const int lane = tid & 63;
    const int m15 = lane & 15;
    const int q = lane >> 4;
    const int row0 = w * 32;

    const float* wbase = wv + (size_t)(2 * kp) * 8192 + col0 + c4 * 4;
    const unsigned short* ab0 = fmb + (row0 + m15) * DD + q * 8;
    const unsigned short* ab1 = ab0 + 16 * DD;

    v4f acc0 = {0.f, 0.f, 0.f, 0.f};
    v4f acc1 = {0.f, 0.f, 0.f, 0.f};
    short8 afr[2][2][4];
    float4 sw0, sw1;

    // prologue: chunk 0
    sw0 = *(const float4*)(wbase);
    sw1 = *(const float4*)(wbase + 8192);
#pragma unroll
    for (int ks = 0; ks < 4; ++ks) {
        afr[0][0][ks] = *(const short8*)(ab0 + ks * 32);
        afr[0][1][ks] = *(const short8*)(ab1 + ks * 32);
    }
    {
        const float* f0 = (const float*)&sw0;
        const float* f1 = (const float*)&sw1;
#pragma unroll
        for (int jj = 0; jj < 4; ++jj)
            *(unsigned*)&Ws[0][c4 * 4 + jj][2 * kp] = pack_bf16(f0[jj], f1[jj]);
    }
    __syncthreads();

#pragma unroll
    for (int c = 0; c < 16; ++c) {
        const int cur = c & 1;
        if (c < 15) {
            const float* wp = wbase + (size_t)(c + 1) * 128 * 8192;
            sw0 = *(const float4*)(wp);
            sw1 = *(const float4*)(wp + 8192);
#pragma unroll
            for (int ks = 0; ks < 4; ++ks) {
                afr[1 - cur][0][ks] = *(const short8*)(ab0 + (c + 1) * 128 + ks * 32);
                afr[1 - cur][1][ks] = *(const short8*)(ab1 + (c + 1) * 128 + ks * 32);
            }
        }
#pragma unroll
        for (int ks = 0; ks < 4; ++ks) {
            short8 bf = *(const short8*)&Ws[cur][m15][ks * 32 + q * 8];
            acc0 = __builtin_amdgcn_mfma_f32_16x16x32_bf16(afr[cur][0][ks], bf, acc0, 0, 0, 0);
            acc1 = __builtin_amdgcn_mfma_f32_16x16x32_bf16(afr[cur][1][ks], bf, acc1, 0, 0, 0);
        }
        if (c < 15) {
            const float* f0 = (const float*)&sw0;
            const float* f1 = (const float*)&sw1;
#pragma unroll
            for (int jj = 0; jj < 4; ++jj)
                *(unsigned*)&Ws[1 - cur][c4 * 4 + jj][2 * kp] = pack_bf16(f0[jj], f1[jj]);
            __syncthreads();
        }
    }

    // epilogue: |acc| -> marg atomics + label-select scatter. C layout: row=q*4+r, col=m15.
    const int v0 = c128 * 4 + (m15 >> 2);  // global vocab id of this lane's column
    const int e = iblk * 4 + (m15 & 3);    // marg/sel element index i*4+j
    const float* a0p = (const float*)&acc0;
    const float* a1p = (const float*)&acc1;
#pragma unroll
    for (int r = 0; r < 4; ++r) {
        int ma = row0 + q * 4 + r;
        int mb = ma + 16;
        float a0 = fabsf(a0p[r]);
        float a1 = fabsf(a1p[r]);
        float s0 = a0 + __shfl_xor(a0, 4); s0 += __shfl_xor(s0, 8);
        float s1 = a1 + __shfl_xor(a1, 4); s1 += __shfl_xor(s1, 8);
        if (m15 < 4) {
            atomicAdd(&marg[ma * 16 + e], s0);
            atomicAdd(&marg[mb * 16 + e], s1);
        }
#pragma unroll
        for (int t = 0; t < TT; ++t) {
            if (slab[ma * 8 + t] == v0) sel[(ma * 8 + t) * 16 + e] = a0;
            if (slab[mb * 8 + t] == v0) sel[(mb * 8 + t) * 16 + e] = a1;
        }
    }
}

// ---------------- phase D: chain products, normalizer, loss ----------------
__global__ __launch_bounds__(128) void phaseD(const float* __restrict__ alphaP,
                                              const float* __restrict__ betaP,
                                              const float* __restrict__ marg,
                                              const float* __restrict__ sel,
                                              float* __restrict__ out) {
    int b = threadIdx.x;
    float alpha[4], beta[4];
#pragma unroll
    for (int r = 0; r < 4; ++r) {
        alpha[r] = fabsf(alphaP[b * 4 + r] + alphaP[512 + b * 4 + r]);
        beta[r]  = fabsf(betaP[b * 4 + r] + betaP[512 + b * 4 + r]);
    }
    const float* sb = sel + b * TT * 16;
    float res[16], tmp[16], mm[16], zm[16];
#pragma unroll
    for (int ee = 0; ee < 16; ++ee) res[ee] = sb[ee];
    for (int t = 1; t < TT; ++t) {
        const float* m = sb + t * 16;
#pragma unroll
        for (int i = 0; i < 4; ++i)
#pragma unroll
            for (int jj = 0; jj < 4; ++jj) {
                float s = 0.f;
#pragma unroll
                for (int k = 0; k < 4; ++k) s += res[i * 4 + k] * m[k * 4 + jj];
                tmp[i * 4 + jj] = s;
            }
#pragma unroll
        for (int ee = 0; ee < 16; ++ee) res[ee] = tmp[ee];
    }
#pragma unroll
    for (int ee = 0; ee < 16; ++ee) { mm[ee] = marg[b * 16 + ee]; zm[ee] = mm[ee]; }
    for (int st = 0; st < TT; ++st) {
#pragma unroll
        for (int i = 0; i < 4; ++i)
#pragma unroll
            for (int jj = 0; jj < 4; ++jj) {
                float s = 0.f;
#pragma unroll
                for (int k = 0; k < 4; ++k) s += zm[i * 4 + k] * mm[k * 4 + jj];
                tmp[i * 4 + jj] = s;
            }
#pragma unroll
        for (int ee = 0; ee < 16; ++ee) zm[ee] = tmp[ee];
    }
    float u = 0.f, z = 0.f;
#pragma unroll
    for (int i = 0; i < 4; ++i) {
#pragma unroll
        for (int jj = 0; jj < 4; ++jj) {
            u += alpha[i] * res[i * 4 + jj] * beta[jj];
            z += alpha[i] * zm[i * 4 + jj] * beta[jj];
        }
    }
    float loss = logf(z) - logf(u);
    __shared__ float red[128];
    red[b] = loss;
    __syncthreads();
    for (int off = 64; off >= 1; off >>= 1) {
        if (b < off) red[b] += red[b + off];
        __syncthreads();
    }
    if (b == 0) out[0] = red[0] * (1.0f / BB);
}

extern "C" void kernel_launch(void* const* d_in, const int* in_sizes, int n_in,
                              void* d_out, int out_size, void* d_ws, size_t ws_size,
                              hipStream_t stream) {
    const float* inp     = (const float*)d_in[0];  // [128,8,2048]
    const int*   labels  = (const int*)d_in[1];    // [128,8]
    const float* w_alpha = (const float*)d_in[2];  // [2048,4]
    const float* w_beta  = (const float*)d_in[3];  // [2048,4]
    const float* wv      = (const float*)d_in[4];  // [2048,8192]
    float* out = (float*)d_out;

    float* ws     = (float*)d_ws;
    float* alphaP = ws;                        // [2][128][4]  = 1024
    float* betaP  = ws + 1024;                 // [2][128][4]  = 1024
    float* marg   = ws + 2048;                 // [128][16]    = 2048
    float* sel    = ws + 4096;                 // [128][8][16] = 16384
    unsigned short* fmb = (unsigned short*)(ws + 20480);  // [128][2048] bf16

    phaseA<<<256, 256, 0, stream>>>(inp, w_alpha, w_beta, fmb, alphaP, betaP, marg);
    phaseB<<<512, 256, 0, stream>>>(fmb, wv, labels, marg, sel);
    phaseD<<<1, 128, 0, stream>>>(alphaP, betaP, marg, sel, out);
}